// Round 11
// baseline (52.074 us; speedup 1.0000x reference)
//
#include <hip/hip_runtime.h>
#include <hip/hip_bf16.h>

#define BN   8
#define NN   1024
#define CIN  256
#define COUT 256
#define HH   4
#define CC   64
#define ALPHA_C 0.2f

typedef __attribute__((ext_vector_type(8))) short short8;
typedef __attribute__((ext_vector_type(4))) float f32x4;

__device__ __forceinline__ unsigned short f2bf(float x) {
    __hip_bfloat16 h = __float2bfloat16(x);
    return *(unsigned short*)&h;
}
__device__ __forceinline__ float bf2f(unsigned short u) {
    return __uint_as_float(((unsigned int)u) << 16);
}

// ---------------- Kernel 0: pack W (fp32) -> Wh/Wl bf16 panels -----------------------
__global__ __launch_bounds__(256) void k0_wpack(
    const float* __restrict__ W, unsigned short* __restrict__ Whp, unsigned short* __restrict__ Wlp)
{
    const int bid = blockIdx.x;          // kc*4 + jg
    const int n = threadIdx.x;
    const int fi = n * 64 + (bid >> 2) * 8 + (bid & 3) * 2;
    const float4* W4 = (const float4*)W;
    float4 wa = W4[fi], wb = W4[fi + 1];
    float xs[8] = {wa.x, wa.y, wa.z, wa.w, wb.x, wb.y, wb.z, wb.w};
    unsigned short hh[8], ll[8];
    #pragma unroll
    for (int e = 0; e < 8; ++e) {
        hh[e] = f2bf(xs[e]);
        ll[e] = f2bf(xs[e] - bf2f(hh[e]));
    }
    *(uint4*)(Whp + ((size_t)bid * 256 + n) * 8) = *(uint4*)hh;
    *(uint4*)(Wlp + ((size_t)bid * 256 + n) * 8) = *(uint4*)ll;
}

// ---------------- Kernel 1: h = X@W^T + b via bf16x3 MFMA ---------------------------
// (unchanged from round 10; panel layout is k2-coalesced)
__global__ __launch_bounds__(1024, 4) void k1_gemm(
    const float* __restrict__ X, const float* __restrict__ bias, const float* __restrict__ a,
    const unsigned short* __restrict__ Whp, const unsigned short* __restrict__ Wlp,
    unsigned short* __restrict__ hbf_p, float* __restrict__ lsrc_t, float* __restrict__ ldst_t)
{
    __shared__ __align__(16) unsigned short Xh[32 * 256];   // 16 KB, XOR-swizzled
    __shared__ __align__(16) unsigned short Xl[32 * 256];   // 16 KB
    __shared__ float lsP[2][8][2][16];                      // [src/dst][no][mq][m16]

    const int bid = blockIdx.x;
    const int row0 = bid * 32;
    const int b  = bid >> 5;
    const int tj = bid & 31;
    const int tid = threadIdx.x;
    const int wv = tid >> 6, l = tid & 63, il = l & 15, jg = l >> 4;
    const int mq = wv >> 3, no = wv & 7;

    {
        const float4* X4 = (const float4*)(X + (size_t)row0 * CIN);
        #pragma unroll
        for (int it = 0; it < 2; ++it) {
            int f = it * 1024 + tid;            // 0..2047 (32 rows x 64 float4)
            int r = f >> 6, k4 = f & 63;
            float4 x = X4[f];
            unsigned short h0 = f2bf(x.x), h1 = f2bf(x.y), h2 = f2bf(x.z), h3 = f2bf(x.w);
            unsigned short l0 = f2bf(x.x - bf2f(h0)), l1 = f2bf(x.y - bf2f(h1));
            unsigned short l2 = f2bf(x.z - bf2f(h2)), l3 = f2bf(x.w - bf2f(h3));
            unsigned short hs[4] = {h0, h1, h2, h3}, ls[4] = {l0, l1, l2, l3};
            int off = r * 512 + ((k4 * 8) ^ ((r & 7) << 4));
            *(uint2*)((char*)Xh + off) = *(uint2*)hs;
            *(uint2*)((char*)Xl + off) = *(uint2*)ls;
        }
    }
    __syncthreads();

    f32x4 acc0 = {0.f, 0.f, 0.f, 0.f}, acc1 = acc0;
    {
        const int abase = (mq * 16 + il) * 512;
        const int swz = (il & 7) << 4;
        const short8* Wh8 = (const short8*)Whp;
        const short8* Wl8 = (const short8*)Wlp;
        const int nb = no * 32 + il;
        #pragma unroll
        for (int kc = 0; kc < 8; ++kc) {
            const int ab = abase + ((kc * 64 + jg * 16) ^ swz);
            short8 Ah = *(const short8*)((const char*)Xh + ab);
            short8 Al = *(const short8*)((const char*)Xl + ab);
            const int pidx = (kc * 4 + jg) * 256 + nb;
            short8 Bh0 = Wh8[pidx],      Bl0 = Wl8[pidx];
            short8 Bh1 = Wh8[pidx + 16], Bl1 = Wl8[pidx + 16];
            acc0 = __builtin_amdgcn_mfma_f32_16x16x32_bf16(Ah, Bh0, acc0, 0, 0, 0);
            acc1 = __builtin_amdgcn_mfma_f32_16x16x32_bf16(Ah, Bh1, acc1, 0, 0, 0);
            acc0 = __builtin_amdgcn_mfma_f32_16x16x32_bf16(Ah, Bl0, acc0, 0, 0, 0);
            acc1 = __builtin_amdgcn_mfma_f32_16x16x32_bf16(Ah, Bl1, acc1, 0, 0, 0);
            acc0 = __builtin_amdgcn_mfma_f32_16x16x32_bf16(Al, Bh0, acc0, 0, 0, 0);
            acc1 = __builtin_amdgcn_mfma_f32_16x16x32_bf16(Al, Bh1, acc1, 0, 0, 0);
        }
    }

    const int c0 = no * 32 + il, c1 = c0 + 16;
    const float bia0 = bias[c0], bia1 = bias[c1];
    const int hh = no >> 1;
    const int cc0 = c0 & 63, cc1 = c1 & 63;
    const float as0 = a[hh * 128 + cc0],      as1 = a[hh * 128 + cc1];
    const float ad0 = a[hh * 128 + 64 + cc0], ad1 = a[hh * 128 + 64 + cc1];

    float v0[4], v1[4], psrc[4], pdst[4];
    #pragma unroll
    for (int r = 0; r < 4; ++r) {
        v0[r] = acc0[r] + bia0;
        v1[r] = acc1[r] + bia1;
        psrc[r] = v0[r] * as0 + v1[r] * as1;
        pdst[r] = v0[r] * ad0 + v1[r] * ad1;
    }
    #pragma unroll
    for (int off = 8; off >= 1; off >>= 1) {
        #pragma unroll
        for (int r = 0; r < 4; ++r) {
            psrc[r] += __shfl_xor(psrc[r], off);
            pdst[r] += __shfl_xor(pdst[r], off);
        }
    }
    __syncthreads();   // all waves done reading Xh/Xl

    unsigned short* hp = Xh;
    #pragma unroll
    for (int r = 0; r < 4; ++r) {
        int m = mq * 16 + 4 * jg + r;
        int base = (m >> 3) * 128 + (m & 7);
        hp[(c0 >> 6) * 2048 + ((c0 & 63) >> 4) * 512 + base + (c0 & 15) * 8] = f2bf(v0[r]);
        hp[(c1 >> 6) * 2048 + ((c1 & 63) >> 4) * 512 + base + (c1 & 15) * 8] = f2bf(v1[r]);
    }
    if (il == 0) {
        #pragma unroll
        for (int r = 0; r < 4; ++r) {
            lsP[0][no][mq][4 * jg + r] = psrc[r];
            lsP[1][no][mq][4 * jg + r] = pdst[r];
        }
    }
    __syncthreads();

    {
        uint4* dst4 = (uint4*)(hbf_p + (size_t)(b * 32 + tj) * 8192);
        dst4[tid] = ((const uint4*)hp)[tid];
    }
    if (tid < 256) {
        int sd = tid >> 7, rem = tid & 127, h2 = rem >> 5, m = rem & 31;
        float v = lsP[sd][2 * h2][m >> 4][m & 15] + lsP[sd][2 * h2 + 1][m >> 4][m & 15];
        float* dst = sd ? ldst_t : lsrc_t;
        dst[((size_t)b * HH + h2) * NN + tj * 32 + m] = v;
    }
}

// ---------------- Kernel 2: masked softmax attention, PV via MFMA -------------------
// grid 256 x 1024thr (16 waves). b = bid&7, i0 = (bid>>3)*32.
// wave wv: h = wv&3, jh = wv>>2 (j-quarter). Each wave owns ALL 32 i-rows (2 A-frags)
// x its head's 64 cols x j-quarter (8 panels: tj = 4*round+jh). B-frag L2 traffic
// halved vs round-10; 2-buffer register pipeline (A,B named bufs, rule-#20 safe);
// 4 independent lsum accumulators. Epilogue: 4-phase RMW reduce across jh in LDS.
__global__ __launch_bounds__(1024, 4) void k2_attn(
    const unsigned short* __restrict__ hbf_p, const int* __restrict__ adj,
    const float* __restrict__ lsrc_t, const float* __restrict__ ldst_t,
    float* __restrict__ out)
{
    __shared__ __align__(16) char smem[32768];   // [adjw 4KB | ldsTbl 16KB] -> epilogue red 32KB
    __shared__ float lsumS[4][4][32];            // [jh][h][row]

    unsigned int (*adjw)[32] = (unsigned int (*)[32])smem;   // [j-word][i-row]
    float* ldsTbl = (float*)(smem + 4096);                   // ldst, 4 heads x 1024

    const int bid = blockIdx.x;
    const int b  = bid & 7;
    const int i0 = (bid >> 3) * 32;
    const int tid = threadIdx.x;
    const int wv = tid >> 6, l = tid & 63, il = l & 15, jg = l >> 4;
    const int h = wv & 3, jh = wv >> 2;

    // ---- prologue: adj bit-pack (2 rows/wave) + ldst table ----
    {
        const int* arow = adj + ((size_t)b * NN + i0 + 2 * wv) * NN;
        #pragma unroll
        for (int rr = 0; rr < 2; ++rr)
            #pragma unroll
            for (int it = 0; it < 16; ++it) {
                int av = arow[rr * NN + it * 64 + l];
                unsigned long long mb = __ballot(av != 0);
                if (l == 0) {
                    adjw[2 * it][2 * wv + rr] = (unsigned int)mb;
                    adjw[2 * it + 1][2 * wv + rr] = (unsigned int)(mb >> 32);
                }
            }
    }
    ((float4*)ldsTbl)[tid] = ((const float4*)(ldst_t + (size_t)b * HH * NN))[tid];

    const float lsrc_v0 = lsrc_t[((size_t)b * HH + h) * NN + i0 + il];
    const float lsrc_v1 = lsrc_t[((size_t)b * HH + h) * NN + i0 + 16 + il];

    __syncthreads();   // adjw + ldsTbl ready

    // ---- mx = max over all j of ldst[h] (valid softmax shift: lrelu monotone) ----
    float mx = -3.4e38f;
    #pragma unroll
    for (int jt = 0; jt < 16; ++jt) mx = fmaxf(mx, ldsTbl[h * 1024 + jt * 64 + l]);
    #pragma unroll
    for (int off = 32; off >= 1; off >>= 1) mx = fmaxf(mx, __shfl_xor(mx, off));
    const float t00 = lsrc_v0 + mx;
    const float t01 = lsrc_v1 + mx;
    const float m_r0 = fmaxf(t00, ALPHA_C * t00);
    const float m_r1 = fmaxf(t01, ALPHA_C * t01);
    float lsA0 = 0.f, lsA1 = 0.f, lsB0 = 0.f, lsB1 = 0.f;

    f32x4 acc00 = {0.f,0.f,0.f,0.f}, acc01 = acc00, acc02 = acc00, acc03 = acc00;
    f32x4 acc10 = acc00, acc11 = acc00, acc12 = acc00, acc13 = acc00;

    // B-frag: panel tj, head h, sub s, lane l at short8 index tj*1024 + h*256 + s*64 + l
    const short8* bfp = (const short8*)(hbf_p + (size_t)b * 32 * 8192);
    const int fb = h * 256 + l;

    short8 A0, A1, A2, A3, B0, B1, B2, B3;
    #define LD(P, RND) { const int t_ = 4 * (RND) + jh;               \
        P##0 = bfp[t_ * 1024 + fb +   0];                             \
        P##1 = bfp[t_ * 1024 + fb +  64];                             \
        P##2 = bfp[t_ * 1024 + fb + 128];                             \
        P##3 = bfp[t_ * 1024 + fb + 192]; }

    #define PEL(AF, E, DV, BW, LSV, MR, LS) {                         \
        float s_ = (LSV) + (DV); s_ = fmaxf(s_, ALPHA_C * s_);        \
        float p_ = __expf(s_ - (MR));                                 \
        p_ = ((BW >> (E)) & 1u) ? p_ : 0.f;                           \
        LS += p_; AF[E] = (short)f2bf(p_); }

    #define ROUND(P, RND) {                                           \
        const int tj_ = 4 * (RND) + jh;                               \
        const unsigned int bw0 = adjw[tj_][il] >> (jg * 8);           \
        const unsigned int bw1 = adjw[tj_][16 + il] >> (jg * 8);      \
        const float* lt_ = ldsTbl + h * 1024 + tj_ * 32 + jg * 8;     \
        const float4 dA = *(const float4*)lt_;                        \
        const float4 dB = *(const float4*)(lt_ + 4);                  \
        short8 af0, af1;                                              \
        PEL(af0, 0, dA.x, bw0, lsrc_v0, m_r0, lsA0)                   \
        PEL(af0, 1, dA.y, bw0, lsrc_v0, m_r0, lsA0)                   \
        PEL(af0, 2, dA.z, bw0, lsrc_v0, m_r0, lsA0)                   \
        PEL(af0, 3, dA.w, bw0, lsrc_v0, m_r0, lsA0)                   \
        PEL(af0, 4, dB.x, bw0, lsrc_v0, m_r0, lsA1)                   \
        PEL(af0, 5, dB.y, bw0, lsrc_v0, m_r0, lsA1)                   \
        PEL(af0, 6, dB.z, bw0, lsrc_v0, m_r0, lsA1)                   \
        PEL(af0, 7, dB.w, bw0, lsrc_v0, m_r0, lsA1)                   \
        PEL(af1, 0, dA.x, bw1, lsrc_v1, m_r1, lsB0)                   \
        PEL(af1, 1, dA.y, bw1, lsrc_v1, m_r1, lsB0)                   \
        PEL(af1, 2, dA.z, bw1, lsrc_v1, m_r1, lsB0)                   \
        PEL(af1, 3, dA.w, bw1, lsrc_v1, m_r1, lsB0)                   \
        PEL(af1, 4, dB.x, bw1, lsrc_v1, m_r1, lsB1)                   \
        PEL(af1, 5, dB.y, bw1, lsrc_v1, m_r1, lsB1)                   \
        PEL(af1, 6, dB.z, bw1, lsrc_v1, m_r1, lsB1)                   \
        PEL(af1, 7, dB.w, bw1, lsrc_v1, m_r1, lsB1)                   \
        acc00 = __builtin_amdgcn_mfma_f32_16x16x32_bf16(af0, P##0, acc00, 0, 0, 0); \
        acc01 = __builtin_amdgcn_mfma_f32_16x16x32_bf16(af0, P##1, acc01, 0, 0, 0); \
        acc02 = __builtin_amdgcn_mfma_f32_16x16x32_bf16(af0, P##2, acc02, 0, 0, 0); \
        acc03 = __builtin_amdgcn_mfma_f32_16x16x32_bf16(af0, P##3, acc03, 0, 0, 0); \
        acc10 = __builtin_amdgcn_mfma_f32_16x16x32_bf16(af1, P##0, acc10, 0, 0, 0); \
        acc11 = __builtin_amdgcn_mfma_f32_16x16x32_bf16(af1, P##1, acc11, 0, 0, 0); \
        acc12 = __builtin_amdgcn_mfma_f32_16x16x32_bf16(af1, P##2, acc12, 0, 0, 0); \
        acc13 = __builtin_amdgcn_mfma_f32_16x16x32_bf16(af1, P##3, acc13, 0, 0, 0); }

    LD(A, 0)
    LD(B, 1)
    for (int rr = 0; rr < 4; ++rr) {
        ROUND(A, 2 * rr)
        if (rr < 3) LD(A, 2 * rr + 2)
        ROUND(B, 2 * rr + 1)
        if (rr < 3) LD(B, 2 * rr + 3)
    }
    #undef LD
    #undef PEL
    #undef ROUND

    // ---- lsum: combine halves, reduce across jg ----
    float ls0 = lsA0 + lsA1, ls1 = lsB0 + lsB1;
    ls0 += __shfl_xor(ls0, 16); ls0 += __shfl_xor(ls0, 32);
    ls1 += __shfl_xor(ls1, 16); ls1 += __shfl_xor(ls1, 32);
    if (l < 16) {
        lsumS[jh][h][l] = ls0;
        lsumS[jh][h][16 + l] = ls1;
    }
    __syncthreads();   // adjw/ldsTbl reads done; red may overlay

    // ---- 4-phase RMW reduction across jh into red[32 rows][256 cols] ----
    float* red = (float*)smem;
    #define STORE1(ACC, MQ, S, OP) {                                              \
        red[((MQ)*16 + 4*jg + 0) * 256 + h * 64 + (S)*16 + il] OP ACC[0];         \
        red[((MQ)*16 + 4*jg + 1) * 256 + h * 64 + (S)*16 + il] OP ACC[1];         \
        red[((MQ)*16 + 4*jg + 2) * 256 + h * 64 + (S)*16 + il] OP ACC[2];         \
        red[((MQ)*16 + 4*jg + 3) * 256 + h * 64 + (S)*16 + il] OP ACC[3]; }
    #define STOREALL(OP) {                                                        \
        STORE1(acc00, 0, 0, OP) STORE1(acc01, 0, 1, OP)                           \
        STORE1(acc02, 0, 2, OP) STORE1(acc03, 0, 3, OP)                           \
        STORE1(acc10, 1, 0, OP) STORE1(acc11, 1, 1, OP)                           \
        STORE1(acc12, 1, 2, OP) STORE1(acc13, 1, 3, OP) }
    if (jh == 0) STOREALL(=)
    __syncthreads();
    if (jh == 1) STOREALL(+=)
    __syncthreads();
    if (jh == 2) STOREALL(+=)
    __syncthreads();
    if (jh == 3) STOREALL(+=)
    __syncthreads();
    #undef STORE1
    #undef STOREALL

    // ---- final: normalize, coalesced store ----
    #pragma unroll
    for (int e = 0; e < 8; ++e) {
        int flat = e * 1024 + tid;
        int m = flat >> 8, c = flat & 255;
        int h2 = c >> 6;
        float ls = lsumS[0][h2][m] + lsumS[1][h2][m] + lsumS[2][h2][m] + lsumS[3][h2][m];
        out[((size_t)b * NN + i0 + m) * 256 + c] = red[m * 256 + c] / ls;
    }
}

extern "C" void kernel_launch(void* const* d_in, const int* in_sizes, int n_in,
                              void* d_out, int out_size, void* d_ws, size_t ws_size,
                              hipStream_t stream) {
    const float* X    = (const float*)d_in[0];
    const int*   adj  = (const int*)  d_in[1];
    const float* W    = (const float*)d_in[2];
    const float* bias = (const float*)d_in[3];
    const float* a    = (const float*)d_in[4];
    float* out = (float*)d_out;

    unsigned short* hbf_p = (unsigned short*)d_ws;                  // 8*32 panels, 4 MB
    float* lsrc_t = (float*)(hbf_p + (size_t)BN * 32 * 8192);       // [b][h][n]
    float* ldst_t = lsrc_t + (size_t)BN * HH * NN;
    unsigned short* Whp = (unsigned short*)(ldst_t + (size_t)BN * HH * NN);  // 128 KB
    unsigned short* Wlp = Whp + 65536;                                        // 128 KB

    k0_wpack<<<32, 256, 0, stream>>>(W, Whp, Wlp);
    k1_gemm<<<256, 1024, 0, stream>>>(X, bias, a, Whp, Wlp, hbf_p, lsrc_t, ldst_t);
    k2_attn<<<256, 1024, 0, stream>>>(hbf_p, adj, lsrc_t, ldst_t, out);
}

// Round 12
// 51.777 us; speedup vs baseline: 1.0057x; 1.0057x over previous
//
#include <hip/hip_runtime.h>
#include <hip/hip_bf16.h>

#define BN   8
#define NN   1024
#define CIN  256
#define COUT 256
#define HH   4
#define CC   64
#define ALPHA_C 0.2f

typedef __attribute__((ext_vector_type(8))) short short8;
typedef __attribute__((ext_vector_type(4))) float f32x4;

__device__ __forceinline__ unsigned short f2bf(float x) {
    __hip_bfloat16 h = __float2bfloat16(x);
    return *(unsigned short*)&h;
}
__device__ __forceinline__ float bf2f(unsigned short u) {
    return __uint_as_float(((unsigned int)u) << 16);
}

// ---------------- Kernel 0: pack W (fp32) -> Wh/Wl bf16 panels -----------------------
__global__ __launch_bounds__(256) void k0_wpack(
    const float* __restrict__ W, unsigned short* __restrict__ Whp, unsigned short* __restrict__ Wlp)
{
    const int bid = blockIdx.x;          // kc*4 + jg
    const int n = threadIdx.x;
    const int fi = n * 64 + (bid >> 2) * 8 + (bid & 3) * 2;
    const float4* W4 = (const float4*)W;
    float4 wa = W4[fi], wb = W4[fi + 1];
    float xs[8] = {wa.x, wa.y, wa.z, wa.w, wb.x, wb.y, wb.z, wb.w};
    unsigned short hh[8], ll[8];
    #pragma unroll
    for (int e = 0; e < 8; ++e) {
        hh[e] = f2bf(xs[e]);
        ll[e] = f2bf(xs[e] - bf2f(hh[e]));
    }
    *(uint4*)(Whp + ((size_t)bid * 256 + n) * 8) = *(uint4*)hh;
    *(uint4*)(Wlp + ((size_t)bid * 256 + n) * 8) = *(uint4*)ll;
}

// ---------------- Kernel 1: h = X@W^T + b via bf16x3 MFMA ---------------------------
// (round-10 structure; launch bounds relaxed to (1024,1) to avoid register strangling)
__global__ __launch_bounds__(1024, 1) void k1_gemm(
    const float* __restrict__ X, const float* __restrict__ bias, const float* __restrict__ a,
    const unsigned short* __restrict__ Whp, const unsigned short* __restrict__ Wlp,
    unsigned short* __restrict__ hbf_p, float* __restrict__ lsrc_t, float* __restrict__ ldst_t)
{
    __shared__ __align__(16) unsigned short Xh[32 * 256];   // 16 KB, XOR-swizzled
    __shared__ __align__(16) unsigned short Xl[32 * 256];   // 16 KB
    __shared__ float lsP[2][8][2][16];                      // [src/dst][no][mq][m16]

    const int bid = blockIdx.x;
    const int row0 = bid * 32;
    const int b  = bid >> 5;
    const int tj = bid & 31;
    const int tid = threadIdx.x;
    const int wv = tid >> 6, l = tid & 63, il = l & 15, jg = l >> 4;
    const int mq = wv >> 3, no = wv & 7;

    {
        const float4* X4 = (const float4*)(X + (size_t)row0 * CIN);
        #pragma unroll
        for (int it = 0; it < 2; ++it) {
            int f = it * 1024 + tid;            // 0..2047 (32 rows x 64 float4)
            int r = f >> 6, k4 = f & 63;
            float4 x = X4[f];
            unsigned short h0 = f2bf(x.x), h1 = f2bf(x.y), h2 = f2bf(x.z), h3 = f2bf(x.w);
            unsigned short l0 = f2bf(x.x - bf2f(h0)), l1 = f2bf(x.y - bf2f(h1));
            unsigned short l2 = f2bf(x.z - bf2f(h2)), l3 = f2bf(x.w - bf2f(h3));
            unsigned short hs[4] = {h0, h1, h2, h3}, ls[4] = {l0, l1, l2, l3};
            int off = r * 512 + ((k4 * 8) ^ ((r & 7) << 4));
            *(uint2*)((char*)Xh + off) = *(uint2*)hs;
            *(uint2*)((char*)Xl + off) = *(uint2*)ls;
        }
    }
    __syncthreads();

    f32x4 acc0 = {0.f, 0.f, 0.f, 0.f}, acc1 = acc0;
    {
        const int abase = (mq * 16 + il) * 512;
        const int swz = (il & 7) << 4;
        const short8* Wh8 = (const short8*)Whp;
        const short8* Wl8 = (const short8*)Wlp;
        const int nb = no * 32 + il;
        #pragma unroll
        for (int kc = 0; kc < 8; ++kc) {
            const int ab = abase + ((kc * 64 + jg * 16) ^ swz);
            short8 Ah = *(const short8*)((const char*)Xh + ab);
            short8 Al = *(const short8*)((const char*)Xl + ab);
            const int pidx = (kc * 4 + jg) * 256 + nb;
            short8 Bh0 = Wh8[pidx],      Bl0 = Wl8[pidx];
            short8 Bh1 = Wh8[pidx + 16], Bl1 = Wl8[pidx + 16];
            acc0 = __builtin_amdgcn_mfma_f32_16x16x32_bf16(Ah, Bh0, acc0, 0, 0, 0);
            acc1 = __builtin_amdgcn_mfma_f32_16x16x32_bf16(Ah, Bh1, acc1, 0, 0, 0);
            acc0 = __builtin_amdgcn_mfma_f32_16x16x32_bf16(Ah, Bl0, acc0, 0, 0, 0);
            acc1 = __builtin_amdgcn_mfma_f32_16x16x32_bf16(Ah, Bl1, acc1, 0, 0, 0);
            acc0 = __builtin_amdgcn_mfma_f32_16x16x32_bf16(Al, Bh0, acc0, 0, 0, 0);
            acc1 = __builtin_amdgcn_mfma_f32_16x16x32_bf16(Al, Bh1, acc1, 0, 0, 0);
        }
    }

    const int c0 = no * 32 + il, c1 = c0 + 16;
    const float bia0 = bias[c0], bia1 = bias[c1];
    const int hh = no >> 1;
    const int cc0 = c0 & 63, cc1 = c1 & 63;
    const float as0 = a[hh * 128 + cc0],      as1 = a[hh * 128 + cc1];
    const float ad0 = a[hh * 128 + 64 + cc0], ad1 = a[hh * 128 + 64 + cc1];

    float v0[4], v1[4], psrc[4], pdst[4];
    #pragma unroll
    for (int r = 0; r < 4; ++r) {
        v0[r] = acc0[r] + bia0;
        v1[r] = acc1[r] + bia1;
        psrc[r] = v0[r] * as0 + v1[r] * as1;
        pdst[r] = v0[r] * ad0 + v1[r] * ad1;
    }
    #pragma unroll
    for (int off = 8; off >= 1; off >>= 1) {
        #pragma unroll
        for (int r = 0; r < 4; ++r) {
            psrc[r] += __shfl_xor(psrc[r], off);
            pdst[r] += __shfl_xor(pdst[r], off);
        }
    }
    __syncthreads();   // all waves done reading Xh/Xl

    unsigned short* hp = Xh;
    #pragma unroll
    for (int r = 0; r < 4; ++r) {
        int m = mq * 16 + 4 * jg + r;
        int base = (m >> 3) * 128 + (m & 7);
        hp[(c0 >> 6) * 2048 + ((c0 & 63) >> 4) * 512 + base + (c0 & 15) * 8] = f2bf(v0[r]);
        hp[(c1 >> 6) * 2048 + ((c1 & 63) >> 4) * 512 + base + (c1 & 15) * 8] = f2bf(v1[r]);
    }
    if (il == 0) {
        #pragma unroll
        for (int r = 0; r < 4; ++r) {
            lsP[0][no][mq][4 * jg + r] = psrc[r];
            lsP[1][no][mq][4 * jg + r] = pdst[r];
        }
    }
    __syncthreads();

    {
        uint4* dst4 = (uint4*)(hbf_p + (size_t)(b * 32 + tj) * 8192);
        dst4[tid] = ((const uint4*)hp)[tid];
    }
    if (tid < 256) {
        int sd = tid >> 7, rem = tid & 127, h2 = rem >> 5, m = rem & 31;
        float v = lsP[sd][2 * h2][m >> 4][m & 15] + lsP[sd][2 * h2 + 1][m >> 4][m & 15];
        float* dst = sd ? ldst_t : lsrc_t;
        dst[((size_t)b * HH + h2) * NN + tj * 32 + m] = v;
    }
}

// ---------------- Kernel 2: masked softmax attention, PV via MFMA -------------------
// grid 256 x 1024thr (16 waves). b = bid&7, i0 = (bid>>3)*32.
// wave wv: h = wv&3, jh = wv>>2 (j-quarter); owns all 32 i-rows x 64 head-cols x
// j-quarter. Round-11 loop kept verbatim; __launch_bounds__(1024,1) so the ~105-VGPR
// live set is NOT spilled (round-11 failure: (1024,4) acted as min-BLOCKS -> 64 VGPR
// cap -> 10 MB/dispatch scratch traffic). Epilogue: 2-phase RMW into red[2] (64 KB).
__global__ __launch_bounds__(1024, 1) void k2_attn(
    const unsigned short* __restrict__ hbf_p, const int* __restrict__ adj,
    const float* __restrict__ lsrc_t, const float* __restrict__ ldst_t,
    float* __restrict__ out)
{
    __shared__ __align__(16) char smem[65536];   // [adjw 4KB | ldsTbl 16KB] -> red[2][32][256]
    __shared__ float lsumS[4][4][32];            // [jh][h][row]

    unsigned int (*adjw)[32] = (unsigned int (*)[32])smem;   // [j-word][i-row]
    float* ldsTbl = (float*)(smem + 4096);                   // ldst, 4 heads x 1024

    const int bid = blockIdx.x;
    const int b  = bid & 7;
    const int i0 = (bid >> 3) * 32;
    const int tid = threadIdx.x;
    const int wv = tid >> 6, l = tid & 63, il = l & 15, jg = l >> 4;
    const int h = wv & 3, jh = wv >> 2;

    // ---- prologue: adj bit-pack (2 rows/wave) + ldst table ----
    {
        const int* arow = adj + ((size_t)b * NN + i0 + 2 * wv) * NN;
        #pragma unroll
        for (int rr = 0; rr < 2; ++rr)
            #pragma unroll
            for (int it = 0; it < 16; ++it) {
                int av = arow[rr * NN + it * 64 + l];
                unsigned long long mb = __ballot(av != 0);
                if (l == 0) {
                    adjw[2 * it][2 * wv + rr] = (unsigned int)mb;
                    adjw[2 * it + 1][2 * wv + rr] = (unsigned int)(mb >> 32);
                }
            }
    }
    ((float4*)ldsTbl)[tid] = ((const float4*)(ldst_t + (size_t)b * HH * NN))[tid];

    const float lsrc_v0 = lsrc_t[((size_t)b * HH + h) * NN + i0 + il];
    const float lsrc_v1 = lsrc_t[((size_t)b * HH + h) * NN + i0 + 16 + il];

    __syncthreads();   // adjw + ldsTbl ready

    // ---- mx = max over all j of ldst[h] (valid softmax shift: lrelu monotone) ----
    float mx = -3.4e38f;
    #pragma unroll
    for (int jt = 0; jt < 16; ++jt) mx = fmaxf(mx, ldsTbl[h * 1024 + jt * 64 + l]);
    #pragma unroll
    for (int off = 32; off >= 1; off >>= 1) mx = fmaxf(mx, __shfl_xor(mx, off));
    const float t00 = lsrc_v0 + mx;
    const float t01 = lsrc_v1 + mx;
    const float m_r0 = fmaxf(t00, ALPHA_C * t00);
    const float m_r1 = fmaxf(t01, ALPHA_C * t01);
    float lsA0 = 0.f, lsA1 = 0.f, lsB0 = 0.f, lsB1 = 0.f;

    f32x4 acc00 = {0.f,0.f,0.f,0.f}, acc01 = acc00, acc02 = acc00, acc03 = acc00;
    f32x4 acc10 = acc00, acc11 = acc00, acc12 = acc00, acc13 = acc00;

    // B-frag: panel tj, head h, sub s, lane l at short8 index tj*1024 + h*256 + s*64 + l
    const short8* bfp = (const short8*)(hbf_p + (size_t)b * 32 * 8192);
    const int fb = h * 256 + l;

    short8 A0, A1, A2, A3, B0, B1, B2, B3;
    #define LD(P, RND) { const int t_ = 4 * (RND) + jh;               \
        P##0 = bfp[t_ * 1024 + fb +   0];                             \
        P##1 = bfp[t_ * 1024 + fb +  64];                             \
        P##2 = bfp[t_ * 1024 + fb + 128];                             \
        P##3 = bfp[t_ * 1024 + fb + 192]; }

    #define PEL(AF, E, DV, BW, LSV, MR, LS) {                         \
        float s_ = (LSV) + (DV); s_ = fmaxf(s_, ALPHA_C * s_);        \
        float p_ = __expf(s_ - (MR));                                 \
        p_ = ((BW >> (E)) & 1u) ? p_ : 0.f;                           \
        LS += p_; AF[E] = (short)f2bf(p_); }

    #define ROUND(P, RND) {                                           \
        const int tj_ = 4 * (RND) + jh;                               \
        const unsigned int bw0 = adjw[tj_][il] >> (jg * 8);           \
        const unsigned int bw1 = adjw[tj_][16 + il] >> (jg * 8);      \
        const float* lt_ = ldsTbl + h * 1024 + tj_ * 32 + jg * 8;     \
        const float4 dA = *(const float4*)lt_;                        \
        const float4 dB = *(const float4*)(lt_ + 4);                  \
        short8 af0, af1;                                              \
        PEL(af0, 0, dA.x, bw0, lsrc_v0, m_r0, lsA0)                   \
        PEL(af0, 1, dA.y, bw0, lsrc_v0, m_r0, lsA0)                   \
        PEL(af0, 2, dA.z, bw0, lsrc_v0, m_r0, lsA0)                   \
        PEL(af0, 3, dA.w, bw0, lsrc_v0, m_r0, lsA0)                   \
        PEL(af0, 4, dB.x, bw0, lsrc_v0, m_r0, lsA1)                   \
        PEL(af0, 5, dB.y, bw0, lsrc_v0, m_r0, lsA1)                   \
        PEL(af0, 6, dB.z, bw0, lsrc_v0, m_r0, lsA1)                   \
        PEL(af0, 7, dB.w, bw0, lsrc_v0, m_r0, lsA1)                   \
        PEL(af1, 0, dA.x, bw1, lsrc_v1, m_r1, lsB0)                   \
        PEL(af1, 1, dA.y, bw1, lsrc_v1, m_r1, lsB0)                   \
        PEL(af1, 2, dA.z, bw1, lsrc_v1, m_r1, lsB0)                   \
        PEL(af1, 3, dA.w, bw1, lsrc_v1, m_r1, lsB0)                   \
        PEL(af1, 4, dB.x, bw1, lsrc_v1, m_r1, lsB1)                   \
        PEL(af1, 5, dB.y, bw1, lsrc_v1, m_r1, lsB1)                   \
        PEL(af1, 6, dB.z, bw1, lsrc_v1, m_r1, lsB1)                   \
        PEL(af1, 7, dB.w, bw1, lsrc_v1, m_r1, lsB1)                   \
        acc00 = __builtin_amdgcn_mfma_f32_16x16x32_bf16(af0, P##0, acc00, 0, 0, 0); \
        acc01 = __builtin_amdgcn_mfma_f32_16x16x32_bf16(af0, P##1, acc01, 0, 0, 0); \
        acc02 = __builtin_amdgcn_mfma_f32_16x16x32_bf16(af0, P##2, acc02, 0, 0, 0); \
        acc03 = __builtin_amdgcn_mfma_f32_16x16x32_bf16(af0, P##3, acc03, 0, 0, 0); \
        acc10 = __builtin_amdgcn_mfma_f32_16x16x32_bf16(af1, P##0, acc10, 0, 0, 0); \
        acc11 = __builtin_amdgcn_mfma_f32_16x16x32_bf16(af1, P##1, acc11, 0, 0, 0); \
        acc12 = __builtin_amdgcn_mfma_f32_16x16x32_bf16(af1, P##2, acc12, 0, 0, 0); \
        acc13 = __builtin_amdgcn_mfma_f32_16x16x32_bf16(af1, P##3, acc13, 0, 0, 0); }

    LD(A, 0)
    LD(B, 1)
    for (int rr = 0; rr < 4; ++rr) {
        ROUND(A, 2 * rr)
        if (rr < 3) LD(A, 2 * rr + 2)
        ROUND(B, 2 * rr + 1)
        if (rr < 3) LD(B, 2 * rr + 3)
    }
    #undef LD
    #undef PEL
    #undef ROUND

    // ---- lsum: combine halves, reduce across jg ----
    float ls0 = lsA0 + lsA1, ls1 = lsB0 + lsB1;
    ls0 += __shfl_xor(ls0, 16); ls0 += __shfl_xor(ls0, 32);
    ls1 += __shfl_xor(ls1, 16); ls1 += __shfl_xor(ls1, 32);
    if (l < 16) {
        lsumS[jh][h][l] = ls0;
        lsumS[jh][h][16 + l] = ls1;
    }
    __syncthreads();   // adjw/ldsTbl reads done; red may overlay

    // ---- 2-phase RMW reduction across jh into red[2][32 rows][256 cols] ----
    float* red = (float*)smem;
    #define STORE1(RB, ACC, MQ, S, OP) {                                          \
        RB[((MQ)*16 + 4*jg + 0) * 256 + h * 64 + (S)*16 + il] OP ACC[0];          \
        RB[((MQ)*16 + 4*jg + 1) * 256 + h * 64 + (S)*16 + il] OP ACC[1];          \
        RB[((MQ)*16 + 4*jg + 2) * 256 + h * 64 + (S)*16 + il] OP ACC[2];          \
        RB[((MQ)*16 + 4*jg + 3) * 256 + h * 64 + (S)*16 + il] OP ACC[3]; }
    #define STOREALL(RB, OP) {                                                    \
        STORE1(RB, acc00, 0, 0, OP) STORE1(RB, acc01, 0, 1, OP)                   \
        STORE1(RB, acc02, 0, 2, OP) STORE1(RB, acc03, 0, 3, OP)                   \
        STORE1(RB, acc10, 1, 0, OP) STORE1(RB, acc11, 1, 1, OP)                   \
        STORE1(RB, acc12, 1, 2, OP) STORE1(RB, acc13, 1, 3, OP) }
    {
        float* rb = red + (jh & 1) * 8192;
        if (jh < 2) STOREALL(rb, =)
        __syncthreads();
        if (jh >= 2) STOREALL(rb, +=)
        __syncthreads();
    }
    #undef STORE1
    #undef STOREALL

    // ---- final: sum buffer pair, normalize, coalesced store ----
    #pragma unroll
    for (int e = 0; e < 8; ++e) {
        int flat = e * 1024 + tid;
        int m = flat >> 8, c = flat & 255;
        int h2 = c >> 6;
        float ls = lsumS[0][h2][m] + lsumS[1][h2][m] + lsumS[2][h2][m] + lsumS[3][h2][m];
        out[((size_t)b * NN + i0 + m) * 256 + c] = (red[flat] + red[8192 + flat]) / ls;
    }
}

extern "C" void kernel_launch(void* const* d_in, const int* in_sizes, int n_in,
                              void* d_out, int out_size, void* d_ws, size_t ws_size,
                              hipStream_t stream) {
    const float* X    = (const float*)d_in[0];
    const int*   adj  = (const int*)  d_in[1];
    const float* W    = (const float*)d_in[2];
    const float* bias = (const float*)d_in[3];
    const float* a    = (const float*)d_in[4];
    float* out = (float*)d_out;

    unsigned short* hbf_p = (unsigned short*)d_ws;                  // 8*32 panels, 4 MB
    float* lsrc_t = (float*)(hbf_p + (size_t)BN * 32 * 8192);       // [b][h][n]
    float* ldst_t = lsrc_t + (size_t)BN * HH * NN;
    unsigned short* Whp = (unsigned short*)(ldst_t + (size_t)BN * HH * NN);  // 128 KB
    unsigned short* Wlp = Whp + 65536;                                        // 128 KB

    k0_wpack<<<32, 256, 0, stream>>>(W, Whp, Wlp);
    k1_gemm<<<256, 1024, 0, stream>>>(X, bias, a, Whp, Wlp, hbf_p, lsrc_t, ldst_t);
    k2_attn<<<256, 1024, 0, stream>>>(hbf_p, adj, lsrc_t, ldst_t, out);
}